// Round 4
// baseline (148.303 us; speedup 1.0000x reference)
//
#include <hip/hip_runtime.h>
#include <stdint.h>

#define B_ROWS 4096
#define C_OUT  2048
#define C_IN   2048
#define EPS    1e-5f

typedef __attribute__((ext_vector_type(8))) short bf16x8;  // 8 bf16 = 4 VGPRs
typedef __attribute__((ext_vector_type(4))) float f32x4;

// RNE f32 -> bf16
__device__ __forceinline__ unsigned short f2bf(float f) {
    uint32_t u = __float_as_uint(f);
    uint32_t r = (u + 0x7fffu + ((u >> 16) & 1u)) >> 16;
    return (unsigned short)r;
}

// One launch converts both x and w (f32 -> bf16, float4-granular)
__global__ void cvt_f32_bf16_kernel(const float* __restrict__ x,
                                    const float* __restrict__ w,
                                    unsigned short* __restrict__ xb,
                                    unsigned short* __restrict__ wb,
                                    int nx4, int nw4) {
    int i = blockIdx.x * blockDim.x + threadIdx.x;
    const float* src;
    unsigned short* dst;
    if (i < nx4) {
        src = x; dst = xb;
    } else {
        i -= nx4;
        if (i >= nw4) return;
        src = w; dst = wb;
    }
    float4 v = ((const float4*)src)[i];
    ushort4 o;
    o.x = f2bf(v.x); o.y = f2bf(v.y); o.z = f2bf(v.z); o.w = f2bf(v.w);
    ((ushort4*)dst)[i] = o;
}

// Fused bf16 GEMM (C = A @ W^T + bias) + GroupNorm(32 groups of 64) + hardtanh.
// Tile 128 rows x 64 cols, BK=64, 4 waves split (row-half wr) x (K-half kh):
// each wave owns a 64x64 output tile over half the K slab (16 MFMA/iter,
// 64x64-wave reuse economics). Grid 1024 = 4 blocks/CU; ~3 resident -> 3
// independent streams/SIMD (vs 2 in R1/R3) to cover the barrier drain.
// K-half pairs combine via LDS (2 phases, contiguous float4 = conflict-free),
// then waves kh==0 do GroupNorm (wave's 64 cols == one full group).
// Swizzle (8 granules/row): (row,q) at q^(row&7); staging q=(t&7)^((t>>3)&7).
__global__ __launch_bounds__(256, 3)
void gemm_gn_kernel(const unsigned short* __restrict__ A,  // [4096][2048] bf16
                    const unsigned short* __restrict__ W,  // [2048][2048] bf16
                    const float* __restrict__ bias,
                    const float* __restrict__ gnw,
                    const float* __restrict__ gnb,
                    float* __restrict__ out) {
    __shared__ __align__(16) unsigned short sA[128 * 64];  // 16 KB
    __shared__ __align__(16) unsigned short sB[64 * 64];   //  8 KB

    const int bc   = blockIdx.x;      // 0..31 col block (64 cols)
    const int br   = blockIdx.y;      // 0..31 row block (128 rows)
    const int t    = threadIdx.x;     // 0..255
    const int lane = t & 63;
    const int wave = t >> 6;          // 0..3
    const int wr   = wave & 1;        // row half (rows wr*64..+64)
    const int kh   = wave >> 1;       // K half (k offset kh*32 within BK=64)
    const int c16  = lane & 15;
    const int quad = lane >> 4;

    f32x4 acc[4][4];
#pragma unroll
    for (int i = 0; i < 4; i++)
#pragma unroll
        for (int j = 0; j < 4; j++) acc[i][j] = (f32x4){0.f, 0.f, 0.f, 0.f};

    // ---- staging addresses ----
    // issue n: granule G = n*256+t; row = G>>3 = n*32+(t>>3); phys q' = t&7;
    // holds global q = (t&7)^(row&7) = (t&7)^((t>>3)&7)  (n*32 == 0 mod 8).
    const int r0 = t >> 3;                          // 0..31
    const int qo = ((t & 7) ^ (r0 & 7)) * 8;        // element offset in row
    const unsigned short* gA = A + (size_t)(br * 128 + r0) * C_IN + qo;
    const unsigned short* gB = W + (size_t)(bc * 64 + r0) * C_IN + qo;

    // fragment read: logical granule q = kh*4+quad lives at q ^ (c16&7)
    const int qs = (((kh << 2) | quad) ^ (c16 & 7)) * 8;

    for (int k0 = 0; k0 < C_IN; k0 += 64) {
#pragma unroll
        for (int n = 0; n < 4; n++)
            __builtin_amdgcn_global_load_lds(
                (const __attribute__((address_space(1))) void*)(gA + (size_t)(n * 32) * C_IN + k0),
                (__attribute__((address_space(3))) void*)(sA + n * 2048 + t * 8), 16, 0, 0);
#pragma unroll
        for (int n = 0; n < 2; n++)
            __builtin_amdgcn_global_load_lds(
                (const __attribute__((address_space(1))) void*)(gB + (size_t)(n * 32) * C_IN + k0),
                (__attribute__((address_space(3))) void*)(sB + n * 2048 + t * 8), 16, 0, 0);
        __syncthreads();

        bf16x8 a[4], b[4];
#pragma unroll
        for (int i = 0; i < 4; i++)
            a[i] = *(const bf16x8*)(sA + (wr * 64 + i * 16 + c16) * 64 + qs);
#pragma unroll
        for (int j = 0; j < 4; j++)
            b[j] = *(const bf16x8*)(sB + (j * 16 + c16) * 64 + qs);
#pragma unroll
        for (int i = 0; i < 4; i++)
#pragma unroll
            for (int j = 0; j < 4; j++)
                acc[i][j] = __builtin_amdgcn_mfma_f32_16x16x32_bf16(a[i], b[j], acc[i][j], 0, 0, 0);
        __syncthreads();
    }

    // ---- combine K-halves via LDS (sA reused: 4096 floats = 16 KB) ----
    // Layout per phase: [pair wr: 2048][ii: 1024][(j*16+c16)*16 + quad*4 + r]
    // -> each (ii,j) write/read is 64 lanes x float4, 1 KB contiguous: no
    // bank conflicts. 2 phases cover i = 0..3.
    float* fbuf = (float*)sA;
#pragma unroll
    for (int ph = 0; ph < 2; ph++) {
        if (kh == 1) {
#pragma unroll
            for (int ii = 0; ii < 2; ii++) {
                int i = ph * 2 + ii;
#pragma unroll
                for (int j = 0; j < 4; j++)
                    *(f32x4*)(fbuf + wr * 2048 + ii * 1024 + (j * 16 + c16) * 16 + quad * 4) = acc[i][j];
            }
        }
        __syncthreads();
        if (kh == 0) {
#pragma unroll
            for (int ii = 0; ii < 2; ii++) {
                int i = ph * 2 + ii;
#pragma unroll
                for (int j = 0; j < 4; j++) {
                    f32x4 v = *(const f32x4*)(fbuf + wr * 2048 + ii * 1024 + (j * 16 + c16) * 16 + quad * 4);
                    acc[i][j] += v;
                }
            }
        }
        __syncthreads();
    }

    if (kh == 1) return;   // all barriers done; waves 2,3 exit

    // ---- epilogue: bias + GroupNorm + hardtanh (waves 0,1 only) ----
    // acc[i][j][r]: row = br*128 + wr*64 + i*16 + quad*4 + r,
    //               col = bc*64 + j*16 + c16. Wave's 64 cols = one group.
    const int colbase = bc * 64;
    const int rowbase = br * 128 + wr * 64;
    float bv[4], gw[4], gb[4];
#pragma unroll
    for (int j = 0; j < 4; j++) {
        int col = colbase + j * 16 + c16;
        bv[j] = bias[col];
        gw[j] = gnw[col];
        gb[j] = gnb[col];
    }
#pragma unroll
    for (int i = 0; i < 4; i++) {
#pragma unroll
        for (int r = 0; r < 4; r++) {
            float s = 0.f, ss = 0.f;
#pragma unroll
            for (int j = 0; j < 4; j++) {
                float v = acc[i][j][r] + bv[j];
                acc[i][j][r] = v;
                s += v;
                ss += v * v;
            }
#pragma unroll
            for (int m = 1; m < 16; m <<= 1) {
                s  += __shfl_xor(s, m, 64);
                ss += __shfl_xor(ss, m, 64);
            }
            float mean = s * (1.f / 64.f);
            float var  = ss * (1.f / 64.f) - mean * mean;
            float rstd = rsqrtf(var + EPS);
            int row = rowbase + i * 16 + quad * 4 + r;
            float* orow = out + (size_t)row * C_OUT;
#pragma unroll
            for (int j = 0; j < 4; j++) {
                float v = (acc[i][j][r] - mean) * rstd * gw[j] + gb[j];
                v = fminf(1.f, fmaxf(-1.f, v));
                orow[colbase + j * 16 + c16] = v;
            }
        }
    }
}

extern "C" void kernel_launch(void* const* d_in, const int* in_sizes, int n_in,
                              void* d_out, int out_size, void* d_ws, size_t ws_size,
                              hipStream_t stream) {
    const float* x    = (const float*)d_in[0];   // [4096, 2048]
    const float* w    = (const float*)d_in[1];   // [2048, 2048]
    const float* bias = (const float*)d_in[2];   // [2048]
    const float* gnw  = (const float*)d_in[3];   // [2048]
    const float* gnb  = (const float*)d_in[4];   // [2048]
    float* out = (float*)d_out;

    unsigned short* xb = (unsigned short*)d_ws;                        // 16 MB
    unsigned short* wb = xb + (size_t)B_ROWS * C_IN;                   //  8 MB

    const int nx4 = B_ROWS * C_IN / 4;   // 2097152
    const int nw4 = C_OUT * C_IN / 4;    // 1048576
    cvt_f32_bf16_kernel<<<(nx4 + nw4 + 255) / 256, 256, 0, stream>>>(x, w, xb, wb, nx4, nw4);

    dim3 grid(C_OUT / 64, B_ROWS / 128);  // (32, 32) = 1024 blocks, 256 thr
    gemm_gn_kernel<<<grid, 256, 0, stream>>>(xb, wb, bias, gnw, gnb, out);
}